// Round 2
// baseline (2602.507 us; speedup 1.0000x reference)
//
#include <hip/hip_runtime.h>
#include <math.h>

#define BB 16
#define LL 100
#define TT 50
#define TE 100
#define HH 200
#define NTL 13               // N tiles of 16 -> 208 (pad 8)
#define NEG_INF_F (-1e30f)

typedef __bf16 bf16;
typedef bf16 bf16x8 __attribute__((ext_vector_type(8)));
typedef float f32x4 __attribute__((ext_vector_type(4)));

#define MFMA __builtin_amdgcn_mfma_f32_16x16x32_bf16

// ---------------------------------------------------------------------------
// Prep: store W^T as MFMA B-fragments, split into hi/lo bf16.
// Fragment index: (((p*NTL + nt)*4 + ks)*64 + lane)*8 + elem
//   k = ks*32 + 8*(lane>>4) + elem   (d index, zero-pad k>=100)
//   n = nt*16 + (lane&15)            (h index, zero-pad n>=200)
// Lane's 8 bf16 are contiguous (16 B) -> one dwordx4 load, coalesced.
// ---------------------------------------------------------------------------
__global__ __launch_bounds__(256)
void wprep_kernel(const float* __restrict__ Wh, const float* __restrict__ Wr,
                  const float* __restrict__ Wt,
                  bf16* __restrict__ hi, bf16* __restrict__ lo) {
    int idx = blockIdx.x * 256 + threadIdx.x;   // grid covers exactly 3*13*2048
    int elem = idx & 7;
    int lane = (idx >> 3) & 63;
    int ks   = (idx >> 9) & 3;
    int pn   = idx >> 11;          // p*NTL + nt
    int nt   = pn % NTL;
    int p    = pn / NTL;
    int k = ks * 32 + 8 * (lane >> 4) + elem;
    int n = nt * 16 + (lane & 15);
    const float* W = (p == 0) ? Wh : (p == 1) ? Wr : Wt;
    float v = (k < TE && n < HH) ? W[n * TE + k] : 0.0f;
    bf16 h = (bf16)v;
    hi[idx] = h;
    lo[idx] = (bf16)(v - (float)h);
}

// Gather A-fragments for one projection (row = triple, k = d), split hi/lo,
// optionally staging the raw f32 row into LDS for the aggregation phase.
__device__ __forceinline__ void gather3(const float* S, bool rv, int lg,
                                        bf16x8 hi[4], bf16x8 lo[4], float* ldst) {
    const f32x4 z4 = {0.f, 0.f, 0.f, 0.f};
    #pragma unroll
    for (int ks = 0; ks < 4; ++ks) {
        f32x4 v0 = z4, v1 = z4;
        if (ks < 3) {
            int d0 = ks * 32 + 8 * lg;
            if (rv) { v0 = *(const f32x4*)(S + d0); v1 = *(const f32x4*)(S + d0 + 4); }
            if (ldst && rv) { *(f32x4*)(ldst + d0) = v0; *(f32x4*)(ldst + d0 + 4) = v1; }
        } else {
            // tail kstep: only d=96..99 valid, group 0 lanes
            if (rv && lg == 0) {
                v0 = *(const f32x4*)(S + 96);
                if (ldst) *(f32x4*)(ldst + 96) = v0;
            }
        }
        bf16x8 h8, l8;
        #pragma unroll
        for (int i = 0; i < 4; ++i) {
            bf16 a = (bf16)v0[i]; h8[i]     = a; l8[i]     = (bf16)(v0[i] - (float)a);
            bf16 b = (bf16)v1[i]; h8[4 + i] = b; l8[4 + i] = (bf16)(v1[i] - (float)b);
        }
        hi[ks] = h8; lo[ks] = l8;
    }
}

__global__ __launch_bounds__(256, 2)
void ccm_mfma_kernel(const float* __restrict__ head, const float* __restrict__ rel,
                     const float* __restrict__ tail,
                     const bf16* __restrict__ WBhi, const bf16* __restrict__ WBlo,
                     const float* __restrict__ bias_h, const float* __restrict__ bias_r,
                     const float* __restrict__ bias_t,
                     const int* __restrict__ tmask, const int* __restrict__ pmask,
                     float* __restrict__ out) {
    __shared__ float sent[2 * TT * TE];   // staged f32 head(0..4999), tail(5000..9999)
    __shared__ float sscore[64];
    __shared__ float sattn[TT];

    const int bl  = blockIdx.x;
    const int tid = threadIdx.x;
    const int wv  = tid >> 6;       // wave = M-tile
    const int l   = tid & 63;
    const int lr  = l & 15;         // A row-in-tile / D col
    const int lg  = l >> 4;         // k-group / D row-group
    const int row = wv * 16 + lr;   // triple index
    const bool rv = row < TT;
    const size_t base = (size_t)bl * TT * TE;

    // ---- A-fragment gather (exactly one global read per element) ----
    bf16x8 AhiH[4], AloH[4], AhiR[4], AloR[4], AhiT[4], AloT[4];
    gather3(head + base + row * TE, rv, lg, AhiH, AloH, &sent[row * TE]);
    gather3(rel  + base + row * TE, rv, lg, AhiR, AloR, nullptr);
    gather3(tail + base + row * TE, rv, lg, AhiT, AloT, &sent[TT * TE + row * TE]);

    // ---- MFMA loop over N tiles, fused score epilogue ----
    float sc[4] = {0.f, 0.f, 0.f, 0.f};
    const size_t pstride = (size_t)NTL * 4 * 64 * 8;   // per-projection frag stride

    #pragma unroll 1
    for (int nt = 0; nt < NTL; ++nt) {
        f32x4 aH = {0,0,0,0}, aR = {0,0,0,0}, aT = {0,0,0,0};
        #pragma unroll 2
        for (int ks = 0; ks < 4; ++ks) {
            const size_t ob = ((size_t)(nt * 4 + ks) * 64 + (size_t)l) * 8;
            bf16x8 wh, wl;
            wh = *(const bf16x8*)(WBhi + ob);
            wl = *(const bf16x8*)(WBlo + ob);
            aH = MFMA(AhiH[ks], wh, aH, 0, 0, 0);
            aH = MFMA(AloH[ks], wh, aH, 0, 0, 0);
            aH = MFMA(AhiH[ks], wl, aH, 0, 0, 0);
            wh = *(const bf16x8*)(WBhi + pstride + ob);
            wl = *(const bf16x8*)(WBlo + pstride + ob);
            aR = MFMA(AhiR[ks], wh, aR, 0, 0, 0);
            aR = MFMA(AloR[ks], wh, aR, 0, 0, 0);
            aR = MFMA(AhiR[ks], wl, aR, 0, 0, 0);
            wh = *(const bf16x8*)(WBhi + 2 * pstride + ob);
            wl = *(const bf16x8*)(WBlo + 2 * pstride + ob);
            aT = MFMA(AhiT[ks], wh, aT, 0, 0, 0);
            aT = MFMA(AloT[ks], wh, aT, 0, 0, 0);
            aT = MFMA(AhiT[ks], wl, aT, 0, 0, 0);
        }
        // epilogue: D elem g -> (row = wv*16 + lg*4 + g, col n = nt*16 + lr)
        const int n = nt * 16 + lr;
        const bool nv = n < HH;
        const float bh = nv ? bias_h[n] : 0.f;   // n>=200: acc is 0 (zero-pad W) -> contrib 0
        const float br = nv ? bias_r[n] : 0.f;
        const float bt = nv ? bias_t[n] : 0.f;
        #pragma unroll
        for (int g = 0; g < 4; ++g) {
            float hv  = aH[g] + bh;
            float tv  = aT[g] + bt;
            float rvv = aR[g] + br;
            float e2  = __expf(2.f * (hv + tv));
            float th  = 1.f - 2.f / (e2 + 1.f);   // tanh; saturates correctly at +-inf
            sc[g] = fmaf(rvv, th, sc[g]);
        }
    }

    // ---- reduce score over the 16 col-lanes (masks 1,2,4,8 keep lg fixed) ----
    #pragma unroll
    for (int g = 0; g < 4; ++g) {
        float s = sc[g];
        s += __shfl_xor(s, 1);
        s += __shfl_xor(s, 2);
        s += __shfl_xor(s, 4);
        s += __shfl_xor(s, 8);
        const int trow = wv * 16 + lg * 4 + g;
        if (lr == 0 && trow < TT) sscore[trow] = s;
    }
    __syncthreads();

    // ---- softmax over T on wave 0 (mask semantics match reference order) ----
    if (tid < 64) {
        const int t = tid;
        const bool valid = t < TT;
        float lgt = valid ? sscore[t] : 0.f;
        const bool tm = valid ? (tmask[bl * TT + t] != 0) : false;
        const bool pm = pmask[bl] != 0;
        float logit = pm ? 0.f : (tm ? NEG_INF_F : lgt);
        float mx = valid ? logit : -3.0e38f;
        #pragma unroll
        for (int o = 32; o; o >>= 1) mx = fmaxf(mx, __shfl_xor(mx, o));
        float e = valid ? __expf(logit - mx) : 0.f;
        float s = e;
        #pragma unroll
        for (int o = 32; o; o >>= 1) s += __shfl_xor(s, o);
        if (valid) sattn[t] = e / s;
    }
    __syncthreads();

    // ---- aggregation from staged f32 LDS: out[bl][e] ----
    if (tid < 2 * TE) {
        const float* src = sent + (tid < TE ? tid : tid + (TT * TE - TE));
        float acc = 0.f;
        #pragma unroll
        for (int t = 0; t < TT; ++t) acc = fmaf(src[t * TE], sattn[t], acc);
        out[(size_t)bl * (2 * TE) + tid] = acc;
    }
}

extern "C" void kernel_launch(void* const* d_in, const int* in_sizes, int n_in,
                              void* d_out, int out_size, void* d_ws, size_t ws_size,
                              hipStream_t stream) {
    const float* head = (const float*)d_in[0];
    const float* rel  = (const float*)d_in[1];
    const float* tail = (const float*)d_in[2];
    const float* Whw  = (const float*)d_in[3];
    const float* Whb  = (const float*)d_in[4];
    const float* Wrw  = (const float*)d_in[5];
    const float* Wrb  = (const float*)d_in[6];
    const float* Wtw  = (const float*)d_in[7];
    const float* Wtb  = (const float*)d_in[8];
    const int* tmask  = (const int*)d_in[9];
    const int* pmask  = (const int*)d_in[10];
    float* out = (float*)d_out;

    bf16* WBhi = (bf16*)d_ws;                    // 79872 bf16 = 159744 B
    bf16* WBlo = WBhi + 3 * NTL * 4 * 64 * 8;    // 16B-aligned offset

    wprep_kernel<<<(3 * NTL * 4 * 64 * 8) / 256, 256, 0, stream>>>(Whw, Wrw, Wtw, WBhi, WBlo);
    ccm_mfma_kernel<<<BB * LL, 256, 0, stream>>>(head, rel, tail, WBhi, WBlo,
                                                 Whb, Wrb, Wtb, tmask, pmask, out);
}

// Round 3
// 206.138 us; speedup vs baseline: 12.6251x; 12.6251x over previous
//
#include <hip/hip_runtime.h>
#include <math.h>

#define BB 16
#define LL 100
#define TT 50
#define TE 100
#define HH 200
#define NTL 13               // N tiles of 16 -> 208 (pad 8)
#define NEG_INF_F (-1e30f)

typedef __bf16 bf16;
typedef bf16 bf16x8 __attribute__((ext_vector_type(8)));
typedef float f32x4 __attribute__((ext_vector_type(4)));

#define MFMA __builtin_amdgcn_mfma_f32_16x16x32_bf16

// ---------------------------------------------------------------------------
// Prep: store W^T as MFMA B-fragments, split into hi/lo bf16.
// Fragment index: (((p*NTL + nt)*4 + ks)*64 + lane)*8 + elem
//   k = ks*32 + 8*(lane>>4) + elem   (d index, zero-pad k>=100)
//   n = nt*16 + (lane&15)            (h index, zero-pad n>=200)
// ---------------------------------------------------------------------------
__global__ __launch_bounds__(256)
void wprep_kernel(const float* __restrict__ Wh, const float* __restrict__ Wr,
                  const float* __restrict__ Wt,
                  bf16* __restrict__ hi, bf16* __restrict__ lo) {
    int idx = blockIdx.x * 256 + threadIdx.x;   // grid covers exactly 3*13*2048
    int elem = idx & 7;
    int lane = (idx >> 3) & 63;
    int ks   = (idx >> 9) & 3;
    int pn   = idx >> 11;          // p*NTL + nt
    int nt   = pn % NTL;
    int p    = pn / NTL;
    int k = ks * 32 + 8 * (lane >> 4) + elem;
    int n = nt * 16 + (lane & 15);
    const float* W = (p == 0) ? Wh : (p == 1) ? Wr : Wt;
    float v = (k < TE && n < HH) ? W[n * TE + k] : 0.0f;
    bf16 h = (bf16)v;
    hi[idx] = h;
    lo[idx] = (bf16)(v - (float)h);
}

// Inline gather: fills HI[0..3], LO[0..3] (bf16x8 each) for one projection.
// All array writes at compile-time-constant indices (SROA-friendly; rule #20).
#define GATHER(SRC, HI, LO, STAGE, DOSTAGE)                                     \
    {                                                                           \
        _Pragma("unroll")                                                       \
        for (int ks_ = 0; ks_ < 4; ++ks_) {                                     \
            f32x4 v0 = {0.f, 0.f, 0.f, 0.f}, v1 = {0.f, 0.f, 0.f, 0.f};         \
            if (ks_ < 3) {                                                      \
                const int d0 = ks_ * 32 + 8 * lg;                               \
                if (rv) {                                                       \
                    v0 = *(const f32x4*)((SRC) + d0);                           \
                    v1 = *(const f32x4*)((SRC) + d0 + 4);                       \
                    if (DOSTAGE) {                                              \
                        *(f32x4*)((STAGE) + d0) = v0;                           \
                        *(f32x4*)((STAGE) + d0 + 4) = v1;                       \
                    }                                                           \
                }                                                               \
            } else if (rv && lg == 0) {                                         \
                v0 = *(const f32x4*)((SRC) + 96);                               \
                if (DOSTAGE) *(f32x4*)((STAGE) + 96) = v0;                      \
            }                                                                   \
            bf16x8 h8, l8;                                                      \
            _Pragma("unroll")                                                   \
            for (int i_ = 0; i_ < 4; ++i_) {                                    \
                bf16 a_ = (bf16)v0[i_];                                         \
                h8[i_] = a_; l8[i_] = (bf16)(v0[i_] - (float)a_);                \
                bf16 b_ = (bf16)v1[i_];                                         \
                h8[4 + i_] = b_; l8[4 + i_] = (bf16)(v1[i_] - (float)b_);        \
            }                                                                   \
            HI[ks_] = h8; LO[ks_] = l8;                                         \
        }                                                                       \
    }

__global__ __launch_bounds__(256)
void ccm_mfma_kernel(const float* __restrict__ head, const float* __restrict__ rel,
                     const float* __restrict__ tail,
                     const bf16* __restrict__ WBhi, const bf16* __restrict__ WBlo,
                     const float* __restrict__ bias_h, const float* __restrict__ bias_r,
                     const float* __restrict__ bias_t,
                     const int* __restrict__ tmask, const int* __restrict__ pmask,
                     float* __restrict__ out) {
    __shared__ float sent[2 * TT * TE];   // staged f32 head(0..4999), tail(5000..9999)
    __shared__ float sscore[64];
    __shared__ float sattn[TT];

    const int bl  = blockIdx.x;
    const int tid = threadIdx.x;
    const int wv  = tid >> 6;       // wave = M-tile
    const int l   = tid & 63;
    const int lr  = l & 15;         // A row-in-tile / D col
    const int lg  = l >> 4;         // k-group / D row-group
    const int row = wv * 16 + lr;   // triple index
    const bool rv = row < TT;
    const size_t base = (size_t)bl * TT * TE + (size_t)row * TE;

    // ---- A-fragment gather (registers only; constant indices throughout) ----
    bf16x8 HhiA[4], HloA[4], RhiA[4], RloA[4], ThiA[4], TloA[4];
    GATHER(head + base, HhiA, HloA, &sent[row * TE], 1);
    GATHER(rel  + base, RhiA, RloA, (float*)nullptr, 0);
    GATHER(tail + base, ThiA, TloA, &sent[TT * TE + row * TE], 1);

    // ---- MFMA loop over N tiles, fused score epilogue ----
    float sc[4] = {0.f, 0.f, 0.f, 0.f};
    const int pstride = NTL * 4 * 64 * 8;   // 26624 bf16 per projection

    #pragma unroll 1
    for (int nt = 0; nt < NTL; ++nt) {
        f32x4 aH = {0, 0, 0, 0}, aR = {0, 0, 0, 0}, aT = {0, 0, 0, 0};
        const int ob0 = nt * 2048 + l * 8;
        #pragma unroll
        for (int ks = 0; ks < 4; ++ks) {
            const int ob = ob0 + ks * 512;
            bf16x8 whH = *(const bf16x8*)(WBhi + ob);
            bf16x8 wlH = *(const bf16x8*)(WBlo + ob);
            bf16x8 whR = *(const bf16x8*)(WBhi + pstride + ob);
            bf16x8 wlR = *(const bf16x8*)(WBlo + pstride + ob);
            bf16x8 whT = *(const bf16x8*)(WBhi + 2 * pstride + ob);
            bf16x8 wlT = *(const bf16x8*)(WBlo + 2 * pstride + ob);
            aH = MFMA(HhiA[ks], whH, aH, 0, 0, 0);
            aR = MFMA(RhiA[ks], whR, aR, 0, 0, 0);
            aT = MFMA(ThiA[ks], whT, aT, 0, 0, 0);
            aH = MFMA(HloA[ks], whH, aH, 0, 0, 0);
            aR = MFMA(RloA[ks], whR, aR, 0, 0, 0);
            aT = MFMA(TloA[ks], whT, aT, 0, 0, 0);
            aH = MFMA(HhiA[ks], wlH, aH, 0, 0, 0);
            aR = MFMA(RhiA[ks], wlR, aR, 0, 0, 0);
            aT = MFMA(ThiA[ks], wlT, aT, 0, 0, 0);
        }
        // epilogue: D elem g -> (row = wv*16 + lg*4 + g, col n = nt*16 + lr)
        const int n = nt * 16 + lr;
        const bool nv = n < HH;
        const float bh = nv ? bias_h[n] : 0.f;   // n>=200: acc is 0 (zero-pad W)
        const float br = nv ? bias_r[n] : 0.f;
        const float bt = nv ? bias_t[n] : 0.f;
        #pragma unroll
        for (int g = 0; g < 4; ++g) {
            float hv  = aH[g] + bh;
            float tv  = aT[g] + bt;
            float rvv = aR[g] + br;
            float e2  = __expf(2.f * (hv + tv));
            float th  = 1.f - 2.f / (e2 + 1.f);   // tanh; saturates at +-inf
            sc[g] = fmaf(rvv, th, sc[g]);
        }
    }

    // ---- reduce score over the 16 col-lanes (masks 1,2,4,8 keep lg fixed) ----
    #pragma unroll
    for (int g = 0; g < 4; ++g) {
        float s = sc[g];
        s += __shfl_xor(s, 1);
        s += __shfl_xor(s, 2);
        s += __shfl_xor(s, 4);
        s += __shfl_xor(s, 8);
        const int trow = wv * 16 + lg * 4 + g;
        if (lr == 0 && trow < TT) sscore[trow] = s;
    }
    __syncthreads();

    // ---- softmax over T on wave 0 (mask semantics match reference order) ----
    if (tid < 64) {
        const int t = tid;
        const bool valid = t < TT;
        float lgt = valid ? sscore[t] : 0.f;
        const bool tm = valid ? (tmask[bl * TT + t] != 0) : false;
        const bool pm = pmask[bl] != 0;
        float logit = pm ? 0.f : (tm ? NEG_INF_F : lgt);
        float mx = valid ? logit : -3.0e38f;
        #pragma unroll
        for (int o = 32; o; o >>= 1) mx = fmaxf(mx, __shfl_xor(mx, o));
        float e = valid ? __expf(logit - mx) : 0.f;
        float s = e;
        #pragma unroll
        for (int o = 32; o; o >>= 1) s += __shfl_xor(s, o);
        if (valid) sattn[t] = e / s;
    }
    __syncthreads();

    // ---- aggregation from staged f32 LDS: out[bl][e] ----
    if (tid < 2 * TE) {
        const float* src = sent + (tid < TE ? tid : tid + (TT * TE - TE));
        float acc = 0.f;
        #pragma unroll
        for (int t = 0; t < TT; ++t) acc = fmaf(src[t * TE], sattn[t], acc);
        out[(size_t)bl * (2 * TE) + tid] = acc;
    }
}

extern "C" void kernel_launch(void* const* d_in, const int* in_sizes, int n_in,
                              void* d_out, int out_size, void* d_ws, size_t ws_size,
                              hipStream_t stream) {
    const float* head = (const float*)d_in[0];
    const float* rel  = (const float*)d_in[1];
    const float* tail = (const float*)d_in[2];
    const float* Whw  = (const float*)d_in[3];
    const float* Whb  = (const float*)d_in[4];
    const float* Wrw  = (const float*)d_in[5];
    const float* Wrb  = (const float*)d_in[6];
    const float* Wtw  = (const float*)d_in[7];
    const float* Wtb  = (const float*)d_in[8];
    const int* tmask  = (const int*)d_in[9];
    const int* pmask  = (const int*)d_in[10];
    float* out = (float*)d_out;

    bf16* WBhi = (bf16*)d_ws;                    // 79872 bf16 = 159744 B
    bf16* WBlo = WBhi + 3 * NTL * 4 * 64 * 8;

    wprep_kernel<<<(3 * NTL * 4 * 64 * 8) / 256, 256, 0, stream>>>(Whw, Wrw, Wtw, WBhi, WBlo);
    ccm_mfma_kernel<<<BB * LL, 256, 0, stream>>>(head, rel, tail, WBhi, WBlo,
                                                 Whb, Wrb, Wtb, tmask, pmask, out);
}